// Round 7
// baseline (627.319 us; speedup 1.0000x reference)
//
#include <hip/hip_runtime.h>

typedef _Float16 f16x8 __attribute__((ext_vector_type(8)));
typedef _Float16 f16x4 __attribute__((ext_vector_type(4)));
typedef float f32x4 __attribute__((ext_vector_type(4)));

#define MFMA16(a, b, c) __builtin_amdgcn_mfma_f32_16x16x32_f16(a, b, c, 0, 0, 0)

// ---- ws byte offsets (all 16B aligned) ----
#define OFF_W1   0u        // eW1  512x512 f16 packed (524288 B)
#define OFF_W2   524288u   // eW2  512x128 (131072 B)
#define OFF_W3   655360u   // eW3  128x64  (16384 B)
#define OFF_W4   671744u   // dW1' 64x128  (16384 B)  = (H64 dW1) * w1c/8
#define OFF_W5   688128u   // dW2  128x32  (8192 B)
#define OFF_W6   696320u   // pW'  32x32   (2048 B)   = (H32 pW) * w2c/sqrt(32)
#define OFF_DB1  698368u   // db1' 128 f32 (512 B)    = db1 + w1b*colsum(dW1)
#define OFF_PB   698880u   // pb'  32 f32  (128 B)    = pb  + w2b*colsum(pW)

__device__ inline void packw(int local, int N, const float* __restrict__ W,
                             _Float16* __restrict__ dst) {
  int j = local & 7;
  int lane = (local >> 3) & 63;
  int fi = local >> 9;
  int NF = N >> 4;
  int nf = fi % NF;
  int kk = fi / NF;
  int k = kk * 32 + ((lane >> 4) << 3) + j;
  int n = (nf << 4) + (lane & 15);
  dst[local] = (_Float16)W[k * N + n];
}

__device__ inline void packh(int local, int N, int K, const float* __restrict__ W,
                             _Float16* __restrict__ dst, float scale) {
  int j = local & 7;
  int lane = (local >> 3) & 63;
  int fi = local >> 9;
  int NF = N >> 4;
  int nf = fi % NF;
  int kk = fi / NF;
  int k = kk * 32 + ((lane >> 4) << 3) + j;
  int n = (nf << 4) + (lane & 15);
  float s = 0.f;
  for (int m = 0; m < K; ++m) {
    float v = W[m * N + n];
    s += (__popc(k & m) & 1) ? -v : v;
  }
  dst[local] = (_Float16)(s * scale);
}

extern "C" __global__ __launch_bounds__(256) void prep_kernel(
    const float* __restrict__ eW1, const float* __restrict__ eW2,
    const float* __restrict__ eW3, const float* __restrict__ dW1,
    const float* __restrict__ dW2, const float* __restrict__ pW,
    const float* __restrict__ w1c, const float* __restrict__ w1b,
    const float* __restrict__ w2c, const float* __restrict__ w2b,
    const float* __restrict__ db1, const float* __restrict__ pb,
    char* __restrict__ ws) {
  int idx = blockIdx.x * 256 + threadIdx.x;
  if (idx < 262144) {
    packw(idx, 512, eW1, (_Float16*)(ws + OFF_W1));
  } else if (idx < 327680) {
    packw(idx - 262144, 128, eW2, (_Float16*)(ws + OFF_W2));
  } else if (idx < 335872) {
    packw(idx - 327680, 64, eW3, (_Float16*)(ws + OFF_W3));
  } else if (idx < 344064) {
    packh(idx - 335872, 128, 64, dW1, (_Float16*)(ws + OFF_W4), w1c[0] * 0.125f);
  } else if (idx < 348160) {
    packw(idx - 344064, 32, dW2, (_Float16*)(ws + OFF_W5));
  } else if (idx < 349184) {
    packh(idx - 348160, 32, 32, pW, (_Float16*)(ws + OFF_W6),
          w2c[0] * 0.17677669529663687f);  // 1/sqrt(32)
  } else if (idx < 349312) {
    int n = idx - 349184;
    float s = 0.f;
    for (int m = 0; m < 64; ++m) s += dW1[m * 128 + n];
    ((float*)(ws + OFF_DB1))[n] = db1[n] + w1b[0] * s;
  } else if (idx < 349344) {
    int n = idx - 349312;
    float s = 0.f;
    for (int m = 0; m < 32; ++m) s += pW[m * 32 + n];
    ((float*)(ws + OFF_PB))[n] = pb[n] + w2b[0] * s;
  }
}

// ---- LDS layout: XOR-swizzled row-major; nu = 16B units per row ----
__device__ inline int hidx(int row, int col, int nu) {
  int u = (col >> 3) ^ ((row & 7) & (nu - 1));
  return row * (nu << 3) + (u << 3) + (col & 7);
}

__device__ inline f16x8 afrag(const _Float16* h, int row, int col, int nu) {
  return *(const f16x8*)(h + hidx(row, col, nu));  // col % 8 == 0 -> 16B aligned
}

// Generic epilogue layer: out[64][16*NFtot]; wave computes MT m-tiles at col-tile nf0.
template <int KK, int NUIN, int NUOUT, bool RELU, int MT>
__device__ inline void layerN(const _Float16* hin, _Float16* hout,
                              const f16x8* __restrict__ Wp,
                              const float* __restrict__ bias, int NFtot, int m0,
                              int nf0, int lane, int g, int rr) {
  f32x4 acc[MT];
#pragma unroll
  for (int m = 0; m < MT; ++m) acc[m] = (f32x4){0.f, 0.f, 0.f, 0.f};
#pragma unroll
  for (int kk = 0; kk < KK; ++kk) {
    f16x8 b = Wp[(kk * NFtot + nf0) * 64 + lane];
#pragma unroll
    for (int m = 0; m < MT; ++m) {
      f16x8 a = afrag(hin, (m0 + m) * 16 + rr, kk * 32 + g * 8, NUIN);
      acc[m] = MFMA16(a, b, acc[m]);
    }
  }
  const int n = nf0 * 16 + rr;
  const float bv = bias[n];
#pragma unroll
  for (int m = 0; m < MT; ++m) {
#pragma unroll
    for (int i = 0; i < 4; ++i) {
      float v = acc[m][i] + bv;
      if (RELU) v = fmaxf(v, 0.f);
      hout[hidx((m0 + m) * 16 + g * 4 + i, n, NUOUT)] = (_Float16)v;
    }
  }
}

// ---- x staging: thread (r = tid>>3, e = tid&7) owns row r, f4-cols t = e*4 + (j&3) + 32*(j>>2).
// Per jj (j>>2): 4 consecutive h0 cols -> one f16x4 (8B) ds_write for R and Z each.
#define LD1(Q, J) Q = xq[e * 4 + ((J) & 3) + 32 * ((J) >> 2)]

#define LDA            \
  do {                 \
    LD1(q0, 0);  LD1(q1, 1);  LD1(q2, 2);  LD1(q3, 3);   \
    LD1(q4, 4);  LD1(q5, 5);  LD1(q6, 6);  LD1(q7, 7);   \
    LD1(q8, 8);  LD1(q9, 9);  LD1(q10, 10); LD1(q11, 11); \
    LD1(q12, 12); LD1(q13, 13); LD1(q14, 14); LD1(q15, 15); \
  } while (0)

#define LDB            \
  do {                 \
    LD1(q16, 16); LD1(q17, 17); LD1(q18, 18); LD1(q19, 19); \
    LD1(q20, 20); LD1(q21, 21); LD1(q22, 22); LD1(q23, 23); \
    LD1(q24, 24); LD1(q25, 25); LD1(q26, 26); LD1(q27, 27); \
    LD1(q28, 28); LD1(q29, 29); LD1(q30, 30); LD1(q31, 31); \
  } while (0)

#define DOTR(V) (_Float16)((V).x * d10 + (V).y * d11 + (V).z * d12 + (V).w * d13)
#define DOTZ(V) (_Float16)((V).x * d20 + (V).y * d21 + (V).z * d22 + (V).w * d23)

#define CONVJJ(QA, QB, QC, QD, JJ)                                        \
  do {                                                                    \
    f16x4 Rv, Zv;                                                         \
    Rv[0] = DOTR(QA); Rv[1] = DOTR(QB); Rv[2] = DOTR(QC); Rv[3] = DOTR(QD); \
    Zv[0] = DOTZ(QA); Zv[1] = DOTZ(QB); Zv[2] = DOTZ(QC); Zv[3] = DOTZ(QD); \
    int u_ = (e >> 1) + 4 * (JJ);                                         \
    int lo_ = r * 512 + ((e & 1) << 2);                                   \
    *(f16x4*)(h0 + lo_ + ((u_ ^ (r & 7)) << 3)) = Rv;                     \
    *(f16x4*)(h0 + lo_ + (((u_ + 32) ^ (r & 7)) << 3)) = Zv;              \
  } while (0)

#define CONVALL                      \
  do {                               \
    CONVJJ(q0, q1, q2, q3, 0);       \
    CONVJJ(q4, q5, q6, q7, 1);       \
    CONVJJ(q8, q9, q10, q11, 2);     \
    CONVJJ(q12, q13, q14, q15, 3);   \
    CONVJJ(q16, q17, q18, q19, 4);   \
    CONVJJ(q20, q21, q22, q23, 5);   \
    CONVJJ(q24, q25, q26, q27, 6);   \
    CONVJJ(q28, q29, q30, q31, 7);   \
  } while (0)

#define L1STEP(KK)                                                        \
  do {                                                                    \
    f16x8 a0_ = afrag(h0, rr, (KK) * 32 + g * 8, 64);                     \
    f16x8 a1_ = afrag(h0, 16 + rr, (KK) * 32 + g * 8, 64);                \
    f16x8 a2_ = afrag(h0, 32 + rr, (KK) * 32 + g * 8, 64);                \
    f16x8 a3_ = afrag(h0, 48 + rr, (KK) * 32 + g * 8, 64);                \
    _Pragma("unroll") for (int nf = 0; nf < 4; ++nf) {                    \
      f16x8 b_ = W1[((KK) * 32 + w * 4 + nf) * 64 + lane];                \
      acc[0][nf] = MFMA16(a0_, b_, acc[0][nf]);                           \
      acc[1][nf] = MFMA16(a1_, b_, acc[1][nf]);                           \
      acc[2][nf] = MFMA16(a2_, b_, acc[2][nf]);                           \
      acc[3][nf] = MFMA16(a3_, b_, acc[3][nf]);                           \
    }                                                                     \
  } while (0)

// ---- persistent fused kernel: 256 WGs (1/CU), 4 blocks of 64 rows each ----
// LDS 152 KB -> 1 WG/CU BY DESIGN: 8 waves, 2/SIMD, ~256-VGPR budget.
//   h0 [64x512 nu64] 64K | h1 [64x512 nu64] 64K | sA (h2/h4, nu16) 16K | sB (h3/h5) 8K
// Phases/block (6 barriers, no x/W latency exposure):
//   L1 (barrier-free 16-kk loop; next block's 32 x-float4 issued inside, held in regs)
//   bar; conv next h0 + L2; bar; L3; bar; L4; bar; L5; bar; L6 (no trailing bar needed)
#define NB 4
#define GRID 256

extern "C" __global__ __launch_bounds__(512, 1) void fused_kernel(
    const float* __restrict__ x, const float* __restrict__ dw1,
    const float* __restrict__ dw2, const float* __restrict__ eb1,
    const float* __restrict__ eb2, const float* __restrict__ eb3,
    const float* __restrict__ db2, const char* __restrict__ ws,
    float* __restrict__ out) {
  __shared__ __align__(16) _Float16 LDS[77824];
  _Float16* const h0 = LDS;           // 32768
  _Float16* const h1 = LDS + 32768;   // 32768
  _Float16* const sA = LDS + 65536;   // 8192 (h2, then h4)
  _Float16* const sB = LDS + 73728;   // 4096 (h3, then h5)

  const int tid = threadIdx.x;
  const int wg = blockIdx.x;
  const int lane = tid & 63;
  const int w = tid >> 6;
  const int g = lane >> 4;
  const int rr = lane & 15;
  const int r = tid >> 3;  // staging row 0..63
  const int e = tid & 7;   // staging sub-col

  const float d10 = dw1[0], d11 = dw1[1], d12 = dw1[2], d13 = dw1[3];
  const float d20 = dw2[0], d21 = dw2[1], d22 = dw2[2], d23 = dw2[3];

  const f16x8* __restrict__ W1 = (const f16x8*)(ws + OFF_W1);
  const f16x8* __restrict__ W2 = (const f16x8*)(ws + OFF_W2);
  const f16x8* __restrict__ W3 = (const f16x8*)(ws + OFF_W3);
  const f16x8* __restrict__ W4 = (const f16x8*)(ws + OFF_W4);
  const f16x8* __restrict__ W5 = (const f16x8*)(ws + OFF_W5);
  const f16x8* __restrict__ W6 = (const f16x8*)(ws + OFF_W6);
  const float* __restrict__ db1p = (const float*)(ws + OFF_DB1);
  const float* __restrict__ pbp = (const float*)(ws + OFF_PB);

  float4 q0, q1, q2, q3, q4, q5, q6, q7, q8, q9, q10, q11, q12, q13, q14, q15;
  float4 q16, q17, q18, q19, q20, q21, q22, q23, q24, q25, q26, q27, q28, q29, q30, q31;

  // ---- prologue: stage + convert block wg into h0 ----
  {
    const float4* __restrict__ xq = (const float4*)x + ((size_t)wg * 64 + r) * 256;
    LDA;
    LDB;
    CONVALL;
  }
  __syncthreads();

  for (int it = 0; it < NB; ++it) {
    const bool pf = (it < NB - 1);
    const float4* __restrict__ xq =
        (const float4*)x + ((size_t)(wg + GRID * (it + 1)) * 64 + r) * 256;

    // ---- L1: h1 = relu(h0 @ eW1 + eb1); barrier-free; x for next block in flight ----
    f32x4 acc[4][4];
#pragma unroll
    for (int m = 0; m < 4; ++m)
#pragma unroll
      for (int n = 0; n < 4; ++n) acc[m][n] = (f32x4){0.f, 0.f, 0.f, 0.f};

    if (pf) LDA;  // 16 loads, in flight across first half of L1
#pragma unroll
    for (int kk = 0; kk < 8; ++kk) L1STEP(kk);
    if (pf) LDB;  // 16 more, in flight across second half
#pragma unroll
    for (int kk = 8; kk < 16; ++kk) L1STEP(kk);

    // h1 store: wave w owns cols [w*64, w*64+64)
#pragma unroll
    for (int mt = 0; mt < 4; ++mt) {
#pragma unroll
      for (int nf = 0; nf < 4; ++nf) {
        const int n = (w * 4 + nf) * 16 + rr;
        const float bv = eb1[n];
#pragma unroll
        for (int i = 0; i < 4; ++i) {
          float v = fmaxf(acc[mt][nf][i] + bv, 0.f);
          h1[hidx(mt * 16 + g * 4 + i, n, 64)] = (_Float16)v;
        }
      }
    }
    __syncthreads();

    // ---- phase 2: conv next h0 (overwrites h0, dead after L1) + L2 GEMM ----
    if (pf) CONVALL;
    layerN<16, 64, 16, true, 4>(h1, sA, W2, eb2, 8, 0, w, lane, g, rr);
    __syncthreads();

    // L3: h3 = h2 @ eW3 + eb3 (FWHT folded fwd)  sA(nu16) -> sB(nu8)
    layerN<4, 16, 8, false, 2>(sA, sB, W3, eb3, 4, (w >> 2) * 2, w & 3, lane, g, rr);
    __syncthreads();
    // L4: h4 = relu(h3 @ dW1' + db1')  sB(nu8) -> sA(nu16)
    layerN<2, 8, 16, true, 4>(sB, sA, W4, db1p, 8, 0, w, lane, g, rr);
    __syncthreads();
    // L5: h5 = h4 @ dW2 + db2  sA(nu16) -> sB(nu4)
    layerN<4, 16, 4, false, 1>(sA, sB, W5, db2, 2, w >> 1, w & 1, lane, g, rr);
    __syncthreads();

    // L6: out = h5 @ pW' + pb'; one tile per wave
    {
      const int m0 = w >> 1;
      const int nf0 = w & 1;
      f16x8 a = afrag(sB, m0 * 16 + rr, g * 8, 4);
      f16x8 b = W6[nf0 * 64 + lane];
      f32x4 o = MFMA16(a, b, ((f32x4){0.f, 0.f, 0.f, 0.f}));
      const int n = nf0 * 16 + rr;
      const float bv = pbp[n];
      const size_t rbase = (size_t)(wg + GRID * it) * 64 + m0 * 16;
#pragma unroll
      for (int i = 0; i < 4; ++i) {
        out[(rbase + g * 4 + i) * 32 + n] = o[i] + bv;
      }
    }
    // no trailing barrier: sB reads complete before any wave passes the next
    // phase-2 barrier; h0 (conv target) untouched until next L1 (bar'd).
  }
}

extern "C" void kernel_launch(void* const* d_in, const int* in_sizes, int n_in,
                              void* d_out, int out_size, void* d_ws, size_t ws_size,
                              hipStream_t stream) {
  const float* x = (const float*)d_in[0];
  const float* dw1 = (const float*)d_in[1];
  const float* dw2 = (const float*)d_in[2];
  const float* eW1 = (const float*)d_in[3];
  const float* eb1 = (const float*)d_in[4];
  const float* eW2 = (const float*)d_in[5];
  const float* eb2 = (const float*)d_in[6];
  const float* eW3 = (const float*)d_in[7];
  const float* eb3 = (const float*)d_in[8];
  const float* w1c = (const float*)d_in[9];
  const float* w1b = (const float*)d_in[10];
  const float* dW1 = (const float*)d_in[11];
  const float* db1 = (const float*)d_in[12];
  const float* dW2 = (const float*)d_in[13];
  const float* db2 = (const float*)d_in[14];
  const float* w2c = (const float*)d_in[15];
  const float* w2b = (const float*)d_in[16];
  const float* pW = (const float*)d_in[17];
  const float* pb = (const float*)d_in[18];
  char* ws = (char*)d_ws;
  float* out = (float*)d_out;

  prep_kernel<<<dim3(1365), dim3(256), 0, stream>>>(eW1, eW2, eW3, dW1, dW2, pW, w1c, w1b,
                                                    w2c, w2b, db1, pb, ws);
  fused_kernel<<<dim3(GRID), dim3(512), 0, stream>>>(x, dw1, dw2, eb1, eb2, eb3, db2, ws,
                                                     out);
}

// Round 8
// 84.012 us; speedup vs baseline: 7.4670x; 7.4670x over previous
//
#include <hip/hip_runtime.h>

typedef _Float16 f16x8 __attribute__((ext_vector_type(8)));
typedef float f32x4 __attribute__((ext_vector_type(4)));

#define MFMA16(a, b, c) __builtin_amdgcn_mfma_f32_16x16x32_f16(a, b, c, 0, 0, 0)

// ---- ws byte offsets (all 16B aligned) ----
#define OFF_W1   0u        // eW1  512x512 f16 packed (524288 B)
#define OFF_W2   524288u   // eW2  512x128 (131072 B)
#define OFF_W3   655360u   // eW3  128x64  (16384 B)
#define OFF_W4   671744u   // dW1' 64x128  (16384 B)  = (H64 dW1) * w1c/8
#define OFF_W5   688128u   // dW2  128x32  (8192 B)
#define OFF_W6   696320u   // pW'  32x32   (2048 B)   = (H32 pW) * w2c/sqrt(32)
#define OFF_DB1  698368u   // db1' 128 f32 (512 B)    = db1 + w1b*colsum(dW1)
#define OFF_PB   698880u   // pb'  32 f32  (128 B)    = pb  + w2b*colsum(pW)

__device__ inline void packw(int local, int N, const float* __restrict__ W,
                             _Float16* __restrict__ dst) {
  int j = local & 7;
  int lane = (local >> 3) & 63;
  int fi = local >> 9;
  int NF = N >> 4;
  int nf = fi % NF;
  int kk = fi / NF;
  int k = kk * 32 + ((lane >> 4) << 3) + j;
  int n = (nf << 4) + (lane & 15);
  dst[local] = (_Float16)W[k * N + n];
}

__device__ inline void packh(int local, int N, int K, const float* __restrict__ W,
                             _Float16* __restrict__ dst, float scale) {
  int j = local & 7;
  int lane = (local >> 3) & 63;
  int fi = local >> 9;
  int NF = N >> 4;
  int nf = fi % NF;
  int kk = fi / NF;
  int k = kk * 32 + ((lane >> 4) << 3) + j;
  int n = (nf << 4) + (lane & 15);
  float s = 0.f;
  for (int m = 0; m < K; ++m) {
    float v = W[m * N + n];
    s += (__popc(k & m) & 1) ? -v : v;
  }
  dst[local] = (_Float16)(s * scale);
}

extern "C" __global__ __launch_bounds__(256) void prep_kernel(
    const float* __restrict__ eW1, const float* __restrict__ eW2,
    const float* __restrict__ eW3, const float* __restrict__ dW1,
    const float* __restrict__ dW2, const float* __restrict__ pW,
    const float* __restrict__ w1c, const float* __restrict__ w1b,
    const float* __restrict__ w2c, const float* __restrict__ w2b,
    const float* __restrict__ db1, const float* __restrict__ pb,
    char* __restrict__ ws) {
  int idx = blockIdx.x * 256 + threadIdx.x;
  if (idx < 262144) {
    packw(idx, 512, eW1, (_Float16*)(ws + OFF_W1));
  } else if (idx < 327680) {
    packw(idx - 262144, 128, eW2, (_Float16*)(ws + OFF_W2));
  } else if (idx < 335872) {
    packw(idx - 327680, 64, eW3, (_Float16*)(ws + OFF_W3));
  } else if (idx < 344064) {
    packh(idx - 335872, 128, 64, dW1, (_Float16*)(ws + OFF_W4), w1c[0] * 0.125f);
  } else if (idx < 348160) {
    packw(idx - 344064, 32, dW2, (_Float16*)(ws + OFF_W5));
  } else if (idx < 349184) {
    packh(idx - 348160, 32, 32, pW, (_Float16*)(ws + OFF_W6),
          w2c[0] * 0.17677669529663687f);  // 1/sqrt(32)
  } else if (idx < 349312) {
    int n = idx - 349184;
    float s = 0.f;
    for (int m = 0; m < 64; ++m) s += dW1[m * 128 + n];
    ((float*)(ws + OFF_DB1))[n] = db1[n] + w1b[0] * s;
  } else if (idx < 349344) {
    int n = idx - 349312;
    float s = 0.f;
    for (int m = 0; m < 32; ++m) s += pW[m * 32 + n];
    ((float*)(ws + OFF_PB))[n] = pb[n] + w2b[0] * s;
  }
}

// ---- LDS layout: XOR-swizzled row-major; nu = 16B units per row ----
__device__ inline int hidx(int row, int col, int nu) {
  int u = (col >> 3) ^ ((row & 7) & (nu - 1));
  return row * (nu << 3) + (u << 3) + (col & 7);
}

__device__ inline f16x8 afrag(const _Float16* h, int row, int col, int nu) {
  return *(const f16x8*)(h + hidx(row, col, nu));  // col % 8 == 0 -> 16B aligned
}

// Generic epilogue layer; wave computes MT m-tiles at column-tile nf0 (m0 in tile units).
template <int KK, int NUIN, int NUOUT, bool RELU, int MT>
__device__ inline void layerN(const _Float16* hin, _Float16* hout,
                              const f16x8* __restrict__ Wp,
                              const float* __restrict__ bias, int NFtot, int m0,
                              int nf0, int lane, int g, int rr) {
  f32x4 acc[MT];
#pragma unroll
  for (int m = 0; m < MT; ++m) acc[m] = (f32x4){0.f, 0.f, 0.f, 0.f};
#pragma unroll
  for (int kk = 0; kk < KK; ++kk) {
    f16x8 b = Wp[(kk * NFtot + nf0) * 64 + lane];
#pragma unroll
    for (int m = 0; m < MT; ++m) {
      f16x8 a = afrag(hin, (m0 + m) * 16 + rr, kk * 32 + g * 8, NUIN);
      acc[m] = MFMA16(a, b, acc[m]);
    }
  }
  const int n = nf0 * 16 + rr;
  const float bv = bias[n];
#pragma unroll
  for (int m = 0; m < MT; ++m) {
#pragma unroll
    for (int i = 0; i < 4; ++i) {
      float v = acc[m][i] + bv;
      if (RELU) v = fmaxf(v, 0.f);
      hout[hidx((m0 + m) * 16 + g * 4 + i, n, NUOUT)] = (_Float16)v;
    }
  }
}

// ---- x staging (per chunk of 128 f32 cols): thread (r8 = tid>>3, e = tid&7)
// loads rows r8 (j=0..3) and r8+64 (j=4..7), f4-col e+8*(j&3): 128B-coalesced.
#define LDC(C)                                              \
  do {                                                      \
    const float4* p0_ = xrow0 + (C) * 32;                   \
    const float4* p1_ = xrow1 + (C) * 32;                   \
    q0 = p0_[e];  q1 = p0_[e + 8];  q2 = p0_[e + 16];  q3 = p0_[e + 24]; \
    q4 = p1_[e];  q5 = p1_[e + 8];  q6 = p1_[e + 16];  q7 = p1_[e + 24]; \
  } while (0)

#define DOTR(V) (_Float16)((V).x * d10 + (V).y * d11 + (V).z * d12 + (V).w * d13)
#define DOTZ(V) (_Float16)((V).x * d20 + (V).y * d21 + (V).z * d22 + (V).w * d23)

// slice idx for (row, within-chunk col = e + 8j), nu4: row*32 + ((j^(row&3))<<3) + e
#define CONVQ(V, ROW, J)                                          \
  do {                                                            \
    int ix_ = (ROW) * 32 + ((((J) ^ ((ROW) & 3))) << 3) + e;      \
    sliceR[ix_] = DOTR(V);                                        \
    sliceZ[ix_] = DOTZ(V);                                        \
  } while (0)

#define CONVC                                                     \
  do {                                                            \
    CONVQ(q0, r8, 0); CONVQ(q1, r8, 1); CONVQ(q2, r8, 2); CONVQ(q3, r8, 3); \
    CONVQ(q4, r8 + 64, 0); CONVQ(q5, r8 + 64, 1); CONVQ(q6, r8 + 64, 2); CONVQ(q7, r8 + 64, 3); \
  } while (0)

// ---- fused kernel: grid 512, one 128-row block per WG, 512 threads ----
// M=128 halves weight traffic/row vs M=64 (682 KB/WG serves 128 rows).
// LDS 144 KB -> 1 WG/CU; 8 waves = 2/SIMD; amdgpu_waves_per_eu(2,2) directs the
// allocator to the 256-reg budget (launch_bounds alone left it at 128 + spill, R6).
//   h1 [128x512 nu64] 128K @0 | slice 16K @65536 (R 4096 f16, Z 4096 f16)
//   after L2 (h1 dead): h2 [128x128 nu16]@0, h3 [128x64 nu8]@16384,
//                       h4 [128x128 nu16]@24576, h5 [128x32 nu4]@40960 (f16 offs)
// x staging regs (q0..q7) live only load->MFMA->conv within one chunk (R5-proven).
#define GRID 512

extern "C" __global__ __launch_bounds__(512)
__attribute__((amdgpu_waves_per_eu(2, 2))) void fused_kernel(
    const float* __restrict__ x, const float* __restrict__ dw1,
    const float* __restrict__ dw2, const float* __restrict__ eb1,
    const float* __restrict__ eb2, const float* __restrict__ eb3,
    const float* __restrict__ db2, const char* __restrict__ ws,
    float* __restrict__ out) {
  __shared__ __align__(16) _Float16 LDS[73728];  // 147456 B
  _Float16* const h1 = LDS;                 // 65536 f16
  _Float16* const sliceR = LDS + 65536;     // 4096 f16 [128x32 nu4]
  _Float16* const sliceZ = LDS + 69632;     // 4096 f16
  _Float16* const h2 = LDS;                 // 16384 f16 [128x128 nu16]
  _Float16* const h3 = LDS + 16384;         // 8192 f16  [128x64 nu8]
  _Float16* const h4 = LDS + 24576;         // 16384 f16 [128x128 nu16]
  _Float16* const h5 = LDS + 40960;         // 4096 f16  [128x32 nu4]

  const int tid = threadIdx.x;
  const int wg = blockIdx.x;
  const int lane = tid & 63;
  const int w = tid >> 6;
  const int g = lane >> 4;
  const int rr = lane & 15;
  const int r8 = tid >> 3;  // staging row 0..63 (and +64)
  const int e = tid & 7;

  const float d10 = dw1[0], d11 = dw1[1], d12 = dw1[2], d13 = dw1[3];
  const float d20 = dw2[0], d21 = dw2[1], d22 = dw2[2], d23 = dw2[3];

  const f16x8* __restrict__ W1 = (const f16x8*)(ws + OFF_W1);
  const f16x8* __restrict__ W2 = (const f16x8*)(ws + OFF_W2);
  const f16x8* __restrict__ W3 = (const f16x8*)(ws + OFF_W3);
  const f16x8* __restrict__ W4 = (const f16x8*)(ws + OFF_W4);
  const f16x8* __restrict__ W5 = (const f16x8*)(ws + OFF_W5);
  const f16x8* __restrict__ W6 = (const f16x8*)(ws + OFF_W6);
  const float* __restrict__ db1p = (const float*)(ws + OFF_DB1);
  const float* __restrict__ pbp = (const float*)(ws + OFF_PB);

  // per-thread x row pointers (256 float4 per 1024-col row)
  const float4* __restrict__ xrow0 =
      (const float4*)x + ((size_t)wg * 128 + r8) * 256;
  const float4* __restrict__ xrow1 = xrow0 + (size_t)64 * 256;

  float4 q0, q1, q2, q3, q4, q5, q6, q7;

  // ---- prologue: chunk 0 ----
  LDC(0);
  CONVC;
  __syncthreads();

  // ---- L1: h1 = relu(h0 @ eW1 + eb1); 8 chunks; acc[8 mt][4 nf] ----
  f32x4 acc[8][4];
#pragma unroll
  for (int m = 0; m < 8; ++m)
#pragma unroll
    for (int n = 0; n < 4; ++n) acc[m][n] = (f32x4){0.f, 0.f, 0.f, 0.f};

  for (int c = 0; c < 8; ++c) {
    if (c < 7) LDC(c + 1);  // in flight across this chunk's MFMA
#pragma unroll
    for (int S = 0; S < 2; ++S) {  // R: kk=c, Z: kk=8+c
      const _Float16* sl = S ? sliceZ : sliceR;
      const int kk = S ? (8 + c) : c;
      f16x8 a0 = afrag(sl, rr, g * 8, 4);
      f16x8 a1 = afrag(sl, 16 + rr, g * 8, 4);
      f16x8 a2 = afrag(sl, 32 + rr, g * 8, 4);
      f16x8 a3 = afrag(sl, 48 + rr, g * 8, 4);
      f16x8 a4 = afrag(sl, 64 + rr, g * 8, 4);
      f16x8 a5 = afrag(sl, 80 + rr, g * 8, 4);
      f16x8 a6 = afrag(sl, 96 + rr, g * 8, 4);
      f16x8 a7 = afrag(sl, 112 + rr, g * 8, 4);
#pragma unroll
      for (int nf = 0; nf < 4; ++nf) {
        f16x8 b = W1[(kk * 32 + w * 4 + nf) * 64 + lane];
        acc[0][nf] = MFMA16(a0, b, acc[0][nf]);
        acc[1][nf] = MFMA16(a1, b, acc[1][nf]);
        acc[2][nf] = MFMA16(a2, b, acc[2][nf]);
        acc[3][nf] = MFMA16(a3, b, acc[3][nf]);
        acc[4][nf] = MFMA16(a4, b, acc[4][nf]);
        acc[5][nf] = MFMA16(a5, b, acc[5][nf]);
        acc[6][nf] = MFMA16(a6, b, acc[6][nf]);
        acc[7][nf] = MFMA16(a7, b, acc[7][nf]);
      }
    }
    if (c < 7) {
      __syncthreads();  // MFMA(c) slice reads done everywhere
      CONVC;            // overwrite slice with chunk c+1
      __syncthreads();  // slice ready
    }
  }

  // h1 store: wave w owns cols [w*64, w*64+64)
#pragma unroll
  for (int mt = 0; mt < 8; ++mt) {
#pragma unroll
    for (int nf = 0; nf < 4; ++nf) {
      const int n = (w * 4 + nf) * 16 + rr;
      const float bv = eb1[n];
#pragma unroll
      for (int i = 0; i < 4; ++i) {
        float v = fmaxf(acc[mt][nf][i] + bv, 0.f);
        h1[hidx(mt * 16 + g * 4 + i, n, 64)] = (_Float16)v;
      }
    }
  }
  __syncthreads();

  // L2: h2 = relu(h1 @ eW2 + eb2)  [128x512]@[512x128]; wave w -> nf0=w, MT=8
  layerN<16, 64, 16, true, 8>(h1, h2, W2, eb2, 8, 0, w, lane, g, rr);
  __syncthreads();
  // L3: h3 = h2 @ eW3 + eb3 (FWHT folded fwd); nf0=w&3, m-half=w>>2, MT=4
  layerN<4, 16, 8, false, 4>(h2, h3, W3, eb3, 4, (w >> 2) * 4, w & 3, lane, g, rr);
  __syncthreads();
  // L4: h4 = relu(h3 @ dW1' + db1'); nf0=w, MT=8
  layerN<2, 8, 16, true, 8>(h3, h4, W4, db1p, 8, 0, w, lane, g, rr);
  __syncthreads();
  // L5: h5 = h4 @ dW2 + db2; nf0=w&1, m-quarter=w>>1, MT=2
  layerN<4, 16, 4, false, 2>(h4, h5, W5, db2, 2, (w >> 1) * 2, w & 1, lane, g, rr);
  __syncthreads();

  // L6: out = h5 @ pW' + pb'; nf0=w&1, m0=(w>>1)*2, MT=2; K=32 (1 kk)
  {
    const int m0 = (w >> 1) * 2;
    const int nf0 = w & 1;
    const int n = nf0 * 16 + rr;
    const float bv = pbp[n];
#pragma unroll
    for (int m = 0; m < 2; ++m) {
      f16x8 a = afrag(h5, (m0 + m) * 16 + rr, g * 8, 4);
      f16x8 b = W6[nf0 * 64 + lane];
      f32x4 o = MFMA16(a, b, ((f32x4){0.f, 0.f, 0.f, 0.f}));
      const size_t rbase = (size_t)wg * 128 + (m0 + m) * 16;
#pragma unroll
      for (int i = 0; i < 4; ++i) {
        out[(rbase + g * 4 + i) * 32 + n] = o[i] + bv;
      }
    }
  }
}

extern "C" void kernel_launch(void* const* d_in, const int* in_sizes, int n_in,
                              void* d_out, int out_size, void* d_ws, size_t ws_size,
                              hipStream_t stream) {
  const float* x = (const float*)d_in[0];
  const float* dw1 = (const float*)d_in[1];
  const float* dw2 = (const float*)d_in[2];
  const float* eW1 = (const float*)d_in[3];
  const float* eb1 = (const float*)d_in[4];
  const float* eW2 = (const float*)d_in[5];
  const float* eb2 = (const float*)d_in[6];
  const float* eW3 = (const float*)d_in[7];
  const float* eb3 = (const float*)d_in[8];
  const float* w1c = (const float*)d_in[9];
  const float* w1b = (const float*)d_in[10];
  const float* dW1 = (const float*)d_in[11];
  const float* db1 = (const float*)d_in[12];
  const float* dW2 = (const float*)d_in[13];
  const float* db2 = (const float*)d_in[14];
  const float* w2c = (const float*)d_in[15];
  const float* w2b = (const float*)d_in[16];
  const float* pW = (const float*)d_in[17];
  const float* pb = (const float*)d_in[18];
  char* ws = (char*)d_ws;
  float* out = (float*)d_out;

  prep_kernel<<<dim3(1365), dim3(256), 0, stream>>>(eW1, eW2, eW3, dW1, dW2, pW, w1c, w1b,
                                                    w2c, w2b, db1, pb, ws);
  fused_kernel<<<dim3(GRID), dim3(512), 0, stream>>>(x, dw1, dw2, eb1, eb2, eb3, db2, ws,
                                                     out);
}